// Round 5
// baseline (545.041 us; speedup 1.0000x reference)
//
#include <hip/hip_runtime.h>
#include <stdint.h>

#define NDIM 64
#define SCAN_ELEMS 2048   // elements per scan block (256 thr x 8)
#define NCHK 16           // edge chunks
#define NGRP 16           // node-range groups
#define RMAX 3200         // max nodes per group (ceil(50000/16)=3125)

// ---------------- weight transpose (k-major) ----------------
// fwT[k*64+o] = fw[o*256+k]; wrT/w1T/w2T[l*4096 + k*64 + o] = W[l][o][k]
__global__ __launch_bounds__(256) void transpose_kernel(
    const float* __restrict__ fw, const float* __restrict__ rootw,
    const float* __restrict__ lin1, const float* __restrict__ lin2,
    float* __restrict__ fwT, float* __restrict__ wrT,
    float* __restrict__ w1T, float* __restrict__ w2T) {
  int e = blockIdx.x * 256 + threadIdx.x;
  if (e < 16384) {
    int o = e >> 8, k = e & 255;
    fwT[k * 64 + o] = fw[e];
  }
  int e2 = e - 16384;
  if (e2 >= 0 && e2 < 12288) {
    int l = e2 >> 12, r = e2 & 4095;
    int o = r >> 6, k = r & 63;
    size_t t = (size_t)l * 4096 + k * 64 + o;
    wrT[t] = rootw[e2];
    w1T[t] = lin1[e2];
    w2T[t] = lin2[e2];
  }
}

// ---------------- CSR build: atomic-free chunked counting sort ----------------
__global__ __launch_bounds__(256) void hist_kernel(
    const int* __restrict__ src, const int* __restrict__ dst,
    int* __restrict__ Hd, int* __restrict__ Hs, int E, int N, int chunk) {
  int c = blockIdx.x, g = blockIdx.y;
  int lo = (int)((long long)N * g / NGRP);
  int hi = (int)((long long)N * (g + 1) / NGRP);
  int range = hi - lo;
  __shared__ int cntd[RMAX];
  __shared__ int cnts[RMAX];
  for (int i = threadIdx.x; i < range; i += 256) { cntd[i] = 0; cnts[i] = 0; }
  __syncthreads();
  int e0 = c * chunk, e1 = min(E, e0 + chunk);
  for (int e = e0 + (int)threadIdx.x * 4; e < e1; e += 1024) {
    if (e + 4 <= e1) {
      int4 s4 = *(const int4*)(src + e);
      int4 d4 = *(const int4*)(dst + e);
      if (d4.x >= lo && d4.x < hi) atomicAdd(&cntd[d4.x - lo], 1);
      if (d4.y >= lo && d4.y < hi) atomicAdd(&cntd[d4.y - lo], 1);
      if (d4.z >= lo && d4.z < hi) atomicAdd(&cntd[d4.z - lo], 1);
      if (d4.w >= lo && d4.w < hi) atomicAdd(&cntd[d4.w - lo], 1);
      if (s4.x >= lo && s4.x < hi) atomicAdd(&cnts[s4.x - lo], 1);
      if (s4.y >= lo && s4.y < hi) atomicAdd(&cnts[s4.y - lo], 1);
      if (s4.z >= lo && s4.z < hi) atomicAdd(&cnts[s4.z - lo], 1);
      if (s4.w >= lo && s4.w < hi) atomicAdd(&cnts[s4.w - lo], 1);
    } else {
      for (int k = e; k < e1; ++k) {
        int s = src[k], d = dst[k];
        if (d >= lo && d < hi) atomicAdd(&cntd[d - lo], 1);
        if (s >= lo && s < hi) atomicAdd(&cnts[s - lo], 1);
      }
    }
  }
  __syncthreads();
  for (int i = threadIdx.x; i < range; i += 256) {
    Hd[(size_t)c * N + lo + i] = cntd[i];
    Hs[(size_t)c * N + lo + i] = cnts[i];
  }
}

__global__ __launch_bounds__(256) void degsum_kernel(
    const int* __restrict__ Hd, const int* __restrict__ Hs,
    int* __restrict__ deg_d, int* __restrict__ deg_s, int N) {
  int n = blockIdx.x * 256 + threadIdx.x;
  if (n >= N) return;
  int sd = 0, ss = 0;
#pragma unroll
  for (int c = 0; c < NCHK; ++c) {
    sd += Hd[(size_t)c * N + n];
    ss += Hs[(size_t)c * N + n];
  }
  deg_d[n] = sd;
  deg_s[n] = ss;
}

__global__ __launch_bounds__(256) void scan_partial(
    const int* __restrict__ deg_d, const int* __restrict__ deg_s,
    int* __restrict__ bsum, int n, int nb) {
  const int* deg = (blockIdx.y == 0) ? deg_d : deg_s;
  int tid = threadIdx.x;
  int base = blockIdx.x * SCAN_ELEMS;
  int s = 0;
#pragma unroll
  for (int j = 0; j < 8; ++j) {
    int i = base + j * 256 + tid;
    if (i < n) s += deg[i];
  }
#pragma unroll
  for (int off = 1; off < 64; off <<= 1) s += __shfl_xor(s, off);
  __shared__ int ws[4];
  if ((tid & 63) == 0) ws[tid >> 6] = s;
  __syncthreads();
  if (tid == 0) bsum[blockIdx.y * nb + blockIdx.x] = ws[0] + ws[1] + ws[2] + ws[3];
}

__global__ __launch_bounds__(256) void scan_bsum(int* __restrict__ bsum, int nb) {
  __shared__ int sh[256];
  int tid = threadIdx.x;
  for (int h = 0; h < 2; ++h) {
    int v = (tid < nb) ? bsum[h * nb + tid] : 0;
    sh[tid] = v;
    __syncthreads();
    for (int off = 1; off < 256; off <<= 1) {
      int t = (tid >= off) ? sh[tid - off] : 0;
      __syncthreads();
      sh[tid] += t;
      __syncthreads();
    }
    if (tid < nb) bsum[h * nb + tid] = sh[tid] - v;  // exclusive
    __syncthreads();
  }
}

__global__ __launch_bounds__(256) void scan_final(
    const int* __restrict__ deg_d, const int* __restrict__ deg_s,
    const int* __restrict__ bsum,
    int* __restrict__ row_d, int* __restrict__ row_s, int n, int nb) {
  const int* deg = (blockIdx.y == 0) ? deg_d : deg_s;
  int* row = (blockIdx.y == 0) ? row_d : row_s;
  int tid = threadIdx.x;
  int lane = tid & 63;
  int e0 = blockIdx.x * SCAN_ELEMS + tid * 8;
  int v[8];
  int s = 0;
#pragma unroll
  for (int j = 0; j < 8; ++j) {
    int i = e0 + j;
    v[j] = (i < n) ? deg[i] : 0;
    s += v[j];
  }
  int incl = s;
#pragma unroll
  for (int off = 1; off < 64; off <<= 1) {
    int t = __shfl_up(incl, off);
    if (lane >= off) incl += t;
  }
  __shared__ int wsum[4];
  if (lane == 63) wsum[tid >> 6] = incl;
  __syncthreads();
  int woff = 0;
  int w = tid >> 6;
  for (int k = 0; k < 4; ++k)
    if (k < w) woff += wsum[k];
  int run = incl - s + woff + bsum[blockIdx.y * nb + blockIdx.x];
#pragma unroll
  for (int j = 0; j < 8; ++j) {
    int i = e0 + j;
    if (i <= n) row[i] = run;
    run += v[j];
  }
}

__global__ __launch_bounds__(256) void cursor_kernel(
    int* __restrict__ Hd, int* __restrict__ Hs,
    const int* __restrict__ row_d, const int* __restrict__ row_s, int N) {
  int n = blockIdx.x * 256 + threadIdx.x;
  if (n >= N) return;
  int rd = row_d[n], rs = row_s[n];
#pragma unroll
  for (int c = 0; c < NCHK; ++c) {
    int t = Hd[(size_t)c * N + n]; Hd[(size_t)c * N + n] = rd; rd += t;
    t = Hs[(size_t)c * N + n];     Hs[(size_t)c * N + n] = rs; rs += t;
  }
}

__global__ __launch_bounds__(256) void scatter_kernel(
    const int* __restrict__ src, const int* __restrict__ dst,
    const int* __restrict__ Hd, const int* __restrict__ Hs,
    int* __restrict__ col_d, int* __restrict__ col_s, int E, int N, int chunk) {
  int c = blockIdx.x, g = blockIdx.y;
  int lo = (int)((long long)N * g / NGRP);
  int hi = (int)((long long)N * (g + 1) / NGRP);
  int range = hi - lo;
  __shared__ int curd[RMAX];
  __shared__ int curs[RMAX];
  for (int i = threadIdx.x; i < range; i += 256) {
    curd[i] = Hd[(size_t)c * N + lo + i];
    curs[i] = Hs[(size_t)c * N + lo + i];
  }
  __syncthreads();
  int e0 = c * chunk, e1 = min(E, e0 + chunk);
  for (int e = e0 + (int)threadIdx.x * 4; e < e1; e += 1024) {
    if (e + 4 <= e1) {
      int4 s4 = *(const int4*)(src + e);
      int4 d4 = *(const int4*)(dst + e);
      if (d4.x >= lo && d4.x < hi) { int p = atomicAdd(&curd[d4.x - lo], 1); col_d[p] = s4.x; }
      if (d4.y >= lo && d4.y < hi) { int p = atomicAdd(&curd[d4.y - lo], 1); col_d[p] = s4.y; }
      if (d4.z >= lo && d4.z < hi) { int p = atomicAdd(&curd[d4.z - lo], 1); col_d[p] = s4.z; }
      if (d4.w >= lo && d4.w < hi) { int p = atomicAdd(&curd[d4.w - lo], 1); col_d[p] = s4.w; }
      if (s4.x >= lo && s4.x < hi) { int p = atomicAdd(&curs[s4.x - lo], 1); col_s[p] = d4.x; }
      if (s4.y >= lo && s4.y < hi) { int p = atomicAdd(&curs[s4.y - lo], 1); col_s[p] = d4.y; }
      if (s4.z >= lo && s4.z < hi) { int p = atomicAdd(&curs[s4.z - lo], 1); col_s[p] = d4.z; }
      if (s4.w >= lo && s4.w < hi) { int p = atomicAdd(&curs[s4.w - lo], 1); col_s[p] = d4.w; }
    } else {
      for (int k = e; k < e1; ++k) {
        int s = src[k], d = dst[k];
        if (d >= lo && d < hi) { int p = atomicAdd(&curd[d - lo], 1); col_d[p] = s; }
        if (s >= lo && s < hi) { int p = atomicAdd(&curs[s - lo], 1); col_s[p] = d; }
      }
    }
  }
}

// ---------------- aggregation: wave per node, lane = feature; y selects direction ----------------

__global__ __launch_bounds__(256) void agg2_kernel(
    const float* __restrict__ h,
    const int* __restrict__ row_d, const int* __restrict__ col_d, float* __restrict__ g1,
    const int* __restrict__ row_s, const int* __restrict__ col_s, float* __restrict__ g2,
    int N) {
  const int* row = (blockIdx.y == 0) ? row_d : row_s;
  const int* col = (blockIdx.y == 0) ? col_d : col_s;
  float* outp = (blockIdx.y == 0) ? g1 : g2;
  int wid = blockIdx.x * 4 + (threadIdx.x >> 6);
  int lane = threadIdx.x & 63;
  if (wid >= N) return;
  int s0 = row[wid], s1 = row[wid + 1];
  float a0 = 0.f, a1 = 0.f, a2 = 0.f, a3 = 0.f;
  int p = s0;
  for (; p + 8 <= s1; p += 8) {
    int n0 = col[p], n1 = col[p + 1], n2 = col[p + 2], n3 = col[p + 3];
    int n4 = col[p + 4], n5 = col[p + 5], n6 = col[p + 6], n7 = col[p + 7];
    a0 += h[(size_t)n0 * NDIM + lane];
    a1 += h[(size_t)n1 * NDIM + lane];
    a2 += h[(size_t)n2 * NDIM + lane];
    a3 += h[(size_t)n3 * NDIM + lane];
    a0 += h[(size_t)n4 * NDIM + lane];
    a1 += h[(size_t)n5 * NDIM + lane];
    a2 += h[(size_t)n6 * NDIM + lane];
    a3 += h[(size_t)n7 * NDIM + lane];
  }
  for (; p + 4 <= s1; p += 4) {
    int n0 = col[p], n1 = col[p + 1], n2 = col[p + 2], n3 = col[p + 3];
    a0 += h[(size_t)n0 * NDIM + lane];
    a1 += h[(size_t)n1 * NDIM + lane];
    a2 += h[(size_t)n2 * NDIM + lane];
    a3 += h[(size_t)n3 * NDIM + lane];
  }
  for (; p < s1; ++p) a0 += h[(size_t)col[p] * NDIM + lane];
  float sum = (a0 + a1) + (a2 + a3);
  int cnt = s1 - s0;
  float inv = cnt > 0 ? 1.f / (float)cnt : 0.f;
  outp[(size_t)wid * NDIM + lane] = sum * inv;
}

// ---------------- combine: wave-split outputs, scalar-broadcast weights ----------------
// 2 output-halves per node, one half per wave. Weights k-major, wave-uniform
// addresses -> s_load broadcast; no LDS.

#define CSTEP(HK, G1K, G2K, K) {                                             \
    const float4* wa_ = (const float4*)(wrT + (K) * 64 + oq * 32);           \
    const float4* wb_ = (const float4*)(w1T + (K) * 64 + oq * 32);           \
    const float4* wc_ = (const float4*)(w2T + (K) * 64 + oq * 32);           \
    _Pragma("unroll")                                                        \
    for (int o4_ = 0; o4_ < 8; ++o4_) {                                      \
      float4 A_ = wa_[o4_], B_ = wb_[o4_], C_ = wc_[o4_];                    \
      acc[4 * o4_ + 0] += (HK) * A_.x + (G1K) * B_.x + (G2K) * C_.x;         \
      acc[4 * o4_ + 1] += (HK) * A_.y + (G1K) * B_.y + (G2K) * C_.y;         \
      acc[4 * o4_ + 2] += (HK) * A_.z + (G1K) * B_.z + (G2K) * C_.z;         \
      acc[4 * o4_ + 3] += (HK) * A_.w + (G1K) * B_.w + (G2K) * C_.w;         \
    } }

__global__ __launch_bounds__(256) void combine_kernel(
    const float* __restrict__ h, const float* __restrict__ g1,
    const float* __restrict__ g2, const float* __restrict__ wrT,
    const float* __restrict__ w1T, const float* __restrict__ w2T,
    const float* __restrict__ bias, float* __restrict__ hout, int N) {
  int w = __builtin_amdgcn_readfirstlane(threadIdx.x >> 6);  // wave id 0..3
  int lane = threadIdx.x & 63;
  int oq = w & 1;                                   // output half
  int node = blockIdx.x * 128 + (w >> 1) * 64 + lane;
  int nodec = node < N ? node : N - 1;
  float acc[32];
#pragma unroll
  for (int o = 0; o < 32; ++o) acc[o] = bias[oq * 32 + o];
  const float4* hp = (const float4*)(h + (size_t)nodec * NDIM);
  const float4* p1 = (const float4*)(g1 + (size_t)nodec * NDIM);
  const float4* p2 = (const float4*)(g2 + (size_t)nodec * NDIM);
  for (int k4 = 0; k4 < 16; ++k4) {
    float4 hv = hp[k4], v1 = p1[k4], v2 = p2[k4];
    int kb = k4 * 4;
    CSTEP(hv.x, v1.x, v2.x, kb + 0);
    CSTEP(hv.y, v1.y, v2.y, kb + 1);
    CSTEP(hv.z, v1.z, v2.z, kb + 2);
    CSTEP(hv.w, v1.w, v2.w, kb + 3);
  }
  if (node < N) {
    float4* op = (float4*)(hout + (size_t)node * NDIM + oq * 32);
#pragma unroll
    for (int o4 = 0; o4 < 8; ++o4) {
      float4 v;
      v.x = fmaxf(acc[4 * o4 + 0], 0.f);
      v.y = fmaxf(acc[4 * o4 + 1], 0.f);
      v.z = fmaxf(acc[4 * o4 + 2], 0.f);
      v.w = fmaxf(acc[4 * o4 + 3], 0.f);
      op[o4] = v;
    }
  }
}

// ---------------- final: 4 output-quarters per node, one per wave ----------------

#define FSTEP(V, K) {                                                        \
    const float4* wp_ = (const float4*)(fwT + (K) * 64 + w * 16);            \
    _Pragma("unroll")                                                        \
    for (int o4_ = 0; o4_ < 4; ++o4_) {                                      \
      float4 W_ = wp_[o4_];                                                  \
      acc[4 * o4_ + 0] += (V) * W_.x;                                        \
      acc[4 * o4_ + 1] += (V) * W_.y;                                        \
      acc[4 * o4_ + 2] += (V) * W_.z;                                        \
      acc[4 * o4_ + 3] += (V) * W_.w;                                        \
    } }

#define FBLOCK(PTR, KBASE) {                                                 \
    const float4* ip_ = (const float4*)((PTR) + (size_t)nodec * NDIM);       \
    for (int k4_ = 0; k4_ < 16; ++k4_) {                                     \
      float4 v_ = ip_[k4_];                                                  \
      int kr_ = (KBASE) + k4_ * 4;                                           \
      FSTEP(v_.x, kr_ + 0);                                                  \
      FSTEP(v_.y, kr_ + 1);                                                  \
      FSTEP(v_.z, kr_ + 2);                                                  \
      FSTEP(v_.w, kr_ + 3);                                                  \
    } }

__global__ __launch_bounds__(256) void final_kernel(
    const float* __restrict__ x, const float* __restrict__ h1,
    const float* __restrict__ h2, const float* __restrict__ h3,
    const float* __restrict__ fwT, const float* __restrict__ fb,
    float* __restrict__ outp, int N) {
  int w = __builtin_amdgcn_readfirstlane(threadIdx.x >> 6);  // output quarter
  int lane = threadIdx.x & 63;
  int node = blockIdx.x * 64 + lane;
  int nodec = node < N ? node : N - 1;
  float acc[16];
#pragma unroll
  for (int o = 0; o < 16; ++o) acc[o] = fb[w * 16 + o];
  FBLOCK(x, 0)
  FBLOCK(h1, 64)
  FBLOCK(h2, 128)
  FBLOCK(h3, 192)
  if (node < N) {
    float4* op = (float4*)(outp + (size_t)node * NDIM + w * 16);
#pragma unroll
    for (int o4 = 0; o4 < 4; ++o4) {
      float4 v;
      v.x = acc[4 * o4 + 0]; v.y = acc[4 * o4 + 1];
      v.z = acc[4 * o4 + 2]; v.w = acc[4 * o4 + 3];
      op[o4] = v;
    }
  }
}

// ---------------- launch ----------------

extern "C" void kernel_launch(void* const* d_in, const int* in_sizes, int n_in,
                              void* d_out, int out_size, void* d_ws, size_t ws_size,
                              hipStream_t stream) {
  const float* x     = (const float*)d_in[0];
  const int*   ei    = (const int*)d_in[1];
  const float* lin1  = (const float*)d_in[2];
  const float* lin2  = (const float*)d_in[3];
  const float* rootw = (const float*)d_in[4];
  const float* rootb = (const float*)d_in[5];
  const float* fw    = (const float*)d_in[6];
  const float* fb    = (const float*)d_in[7];
  float* out = (float*)d_out;

  int N = in_sizes[0] / NDIM;
  int E = in_sizes[1] / 2;
  const int* src = ei;
  const int* dst = ei + E;

  int* ip = (int*)d_ws;
  int* Hd    = ip; ip += (size_t)NCHK * N;
  int* Hs    = ip; ip += (size_t)NCHK * N;
  int* deg_d = ip; ip += N;
  int* deg_s = ip; ip += N;
  int* row_d = ip; ip += N + 1;
  int* row_s = ip; ip += N + 1;
  int* bsum  = ip; ip += 256;
  int* col_d = ip; ip += E;
  int* col_s = ip; ip += E;
  uintptr_t fbase = (((uintptr_t)ip) + 255) & ~(uintptr_t)255;
  float* fwT = (float*)fbase;
  float* wrT = fwT + 16384;
  float* w1T = wrT + 12288;
  float* w2T = w1T + 12288;
  float* h1  = w2T + 12288;
  float* h2 = h1 + (size_t)N * NDIM;
  float* h3 = h2 + (size_t)N * NDIM;
  float* g1 = h3 + (size_t)N * NDIM;
  float* g2 = g1 + (size_t)N * NDIM;

  int chunk = (E + NCHK - 1) / NCHK;
  int nb = (N + SCAN_ELEMS - 1) / SCAN_ELEMS;
  int nblk = (N + 255) / 256;

  transpose_kernel<<<112, 256, 0, stream>>>(fw, rootw, lin1, lin2, fwT, wrT, w1T, w2T);
  hist_kernel<<<dim3(NCHK, NGRP), 256, 0, stream>>>(src, dst, Hd, Hs, E, N, chunk);
  degsum_kernel<<<nblk, 256, 0, stream>>>(Hd, Hs, deg_d, deg_s, N);
  scan_partial<<<dim3(nb, 2), 256, 0, stream>>>(deg_d, deg_s, bsum, N, nb);
  scan_bsum<<<1, 256, 0, stream>>>(bsum, nb);
  scan_final<<<dim3(nb, 2), 256, 0, stream>>>(deg_d, deg_s, bsum, row_d, row_s, N, nb);
  cursor_kernel<<<nblk, 256, 0, stream>>>(Hd, Hs, row_d, row_s, N);
  scatter_kernel<<<dim3(NCHK, NGRP), 256, 0, stream>>>(src, dst, Hd, Hs,
                                                       col_d, col_s, E, N, chunk);

  int ab = (N + 3) / 4;
  int cgrid = (N + 127) / 128;   // combine: 128 nodes/block (2 waves split outputs)
  int fgrid = (N + 63) / 64;     // final: 64 nodes/block (4 waves split outputs)
  const float* hbufs[4] = {x, h1, h2, h3};
  for (int l = 0; l < 3; ++l) {
    const float* hin = hbufs[l];
    float* hout = (float*)hbufs[l + 1];
    agg2_kernel<<<dim3(ab, 2), 256, 0, stream>>>(hin, row_d, col_d, g1,
                                                 row_s, col_s, g2, N);
    combine_kernel<<<cgrid, 256, 0, stream>>>(hin, g1, g2,
                                              wrT + (size_t)l * 4096,
                                              w1T + (size_t)l * 4096,
                                              w2T + (size_t)l * 4096,
                                              rootb + (size_t)l * 64, hout, N);
  }
  final_kernel<<<fgrid, 256, 0, stream>>>(x, h1, h2, h3, fwT, fb, out, N);
}

// Round 6
// 449.096 us; speedup vs baseline: 1.2136x; 1.2136x over previous
//
#include <hip/hip_runtime.h>
#include <stdint.h>

#define NDIM 64
#define SCAN_ELEMS 2048   // elements per scan block (256 thr x 8)
#define NCHK 16           // edge chunks
#define NGRP 16           // node-range groups
#define RMAX 3200         // max nodes per group (ceil(50000/16)=3125)

// ---------------- weight transpose (k-major) ----------------
__global__ __launch_bounds__(256) void transpose_kernel(
    const float* __restrict__ fw, const float* __restrict__ rootw,
    const float* __restrict__ lin1, const float* __restrict__ lin2,
    float* __restrict__ fwT, float* __restrict__ wrT,
    float* __restrict__ w1T, float* __restrict__ w2T) {
  int e = blockIdx.x * 256 + threadIdx.x;
  if (e < 16384) {
    int o = e >> 8, k = e & 255;
    fwT[k * 64 + o] = fw[e];
  }
  int e2 = e - 16384;
  if (e2 >= 0 && e2 < 12288) {
    int l = e2 >> 12, r = e2 & 4095;
    int o = r >> 6, k = r & 63;
    size_t t = (size_t)l * 4096 + k * 64 + o;
    wrT[t] = rootw[e2];
    w1T[t] = lin1[e2];
    w2T[t] = lin2[e2];
  }
}

// ---------------- CSR build: atomic-free chunked counting sort ----------------
__global__ __launch_bounds__(256) void hist_kernel(
    const int* __restrict__ src, const int* __restrict__ dst,
    int* __restrict__ Hd, int* __restrict__ Hs, int E, int N, int chunk) {
  int c = blockIdx.x, g = blockIdx.y;
  int lo = (int)((long long)N * g / NGRP);
  int hi = (int)((long long)N * (g + 1) / NGRP);
  int range = hi - lo;
  __shared__ int cntd[RMAX];
  __shared__ int cnts[RMAX];
  for (int i = threadIdx.x; i < range; i += 256) { cntd[i] = 0; cnts[i] = 0; }
  __syncthreads();
  int e0 = c * chunk, e1 = min(E, e0 + chunk);
  for (int e = e0 + (int)threadIdx.x * 4; e < e1; e += 1024) {
    if (e + 4 <= e1) {
      int4 s4 = *(const int4*)(src + e);
      int4 d4 = *(const int4*)(dst + e);
      if (d4.x >= lo && d4.x < hi) atomicAdd(&cntd[d4.x - lo], 1);
      if (d4.y >= lo && d4.y < hi) atomicAdd(&cntd[d4.y - lo], 1);
      if (d4.z >= lo && d4.z < hi) atomicAdd(&cntd[d4.z - lo], 1);
      if (d4.w >= lo && d4.w < hi) atomicAdd(&cntd[d4.w - lo], 1);
      if (s4.x >= lo && s4.x < hi) atomicAdd(&cnts[s4.x - lo], 1);
      if (s4.y >= lo && s4.y < hi) atomicAdd(&cnts[s4.y - lo], 1);
      if (s4.z >= lo && s4.z < hi) atomicAdd(&cnts[s4.z - lo], 1);
      if (s4.w >= lo && s4.w < hi) atomicAdd(&cnts[s4.w - lo], 1);
    } else {
      for (int k = e; k < e1; ++k) {
        int s = src[k], d = dst[k];
        if (d >= lo && d < hi) atomicAdd(&cntd[d - lo], 1);
        if (s >= lo && s < hi) atomicAdd(&cnts[s - lo], 1);
      }
    }
  }
  __syncthreads();
  for (int i = threadIdx.x; i < range; i += 256) {
    Hd[(size_t)c * N + lo + i] = cntd[i];
    Hs[(size_t)c * N + lo + i] = cnts[i];
  }
}

__global__ __launch_bounds__(256) void degsum_kernel(
    const int* __restrict__ Hd, const int* __restrict__ Hs,
    int* __restrict__ deg_d, int* __restrict__ deg_s, int N) {
  int n = blockIdx.x * 256 + threadIdx.x;
  if (n >= N) return;
  int sd = 0, ss = 0;
#pragma unroll
  for (int c = 0; c < NCHK; ++c) {
    sd += Hd[(size_t)c * N + n];
    ss += Hs[(size_t)c * N + n];
  }
  deg_d[n] = sd;
  deg_s[n] = ss;
}

__global__ __launch_bounds__(256) void scan_partial(
    const int* __restrict__ deg_d, const int* __restrict__ deg_s,
    int* __restrict__ bsum, int n, int nb) {
  const int* deg = (blockIdx.y == 0) ? deg_d : deg_s;
  int tid = threadIdx.x;
  int base = blockIdx.x * SCAN_ELEMS;
  int s = 0;
#pragma unroll
  for (int j = 0; j < 8; ++j) {
    int i = base + j * 256 + tid;
    if (i < n) s += deg[i];
  }
#pragma unroll
  for (int off = 1; off < 64; off <<= 1) s += __shfl_xor(s, off);
  __shared__ int ws[4];
  if ((tid & 63) == 0) ws[tid >> 6] = s;
  __syncthreads();
  if (tid == 0) bsum[blockIdx.y * nb + blockIdx.x] = ws[0] + ws[1] + ws[2] + ws[3];
}

__global__ __launch_bounds__(256) void scan_bsum(int* __restrict__ bsum, int nb) {
  __shared__ int sh[256];
  int tid = threadIdx.x;
  for (int h = 0; h < 2; ++h) {
    int v = (tid < nb) ? bsum[h * nb + tid] : 0;
    sh[tid] = v;
    __syncthreads();
    for (int off = 1; off < 256; off <<= 1) {
      int t = (tid >= off) ? sh[tid - off] : 0;
      __syncthreads();
      sh[tid] += t;
      __syncthreads();
    }
    if (tid < nb) bsum[h * nb + tid] = sh[tid] - v;  // exclusive
    __syncthreads();
  }
}

__global__ __launch_bounds__(256) void scan_final(
    const int* __restrict__ deg_d, const int* __restrict__ deg_s,
    const int* __restrict__ bsum,
    int* __restrict__ row_d, int* __restrict__ row_s, int n, int nb) {
  const int* deg = (blockIdx.y == 0) ? deg_d : deg_s;
  int* row = (blockIdx.y == 0) ? row_d : row_s;
  int tid = threadIdx.x;
  int lane = tid & 63;
  int e0 = blockIdx.x * SCAN_ELEMS + tid * 8;
  int v[8];
  int s = 0;
#pragma unroll
  for (int j = 0; j < 8; ++j) {
    int i = e0 + j;
    v[j] = (i < n) ? deg[i] : 0;
    s += v[j];
  }
  int incl = s;
#pragma unroll
  for (int off = 1; off < 64; off <<= 1) {
    int t = __shfl_up(incl, off);
    if (lane >= off) incl += t;
  }
  __shared__ int wsum[4];
  if (lane == 63) wsum[tid >> 6] = incl;
  __syncthreads();
  int woff = 0;
  int w = tid >> 6;
  for (int k = 0; k < 4; ++k)
    if (k < w) woff += wsum[k];
  int run = incl - s + woff + bsum[blockIdx.y * nb + blockIdx.x];
#pragma unroll
  for (int j = 0; j < 8; ++j) {
    int i = e0 + j;
    if (i <= n) row[i] = run;
    run += v[j];
  }
}

__global__ __launch_bounds__(256) void cursor_kernel(
    int* __restrict__ Hd, int* __restrict__ Hs,
    const int* __restrict__ row_d, const int* __restrict__ row_s, int N) {
  int n = blockIdx.x * 256 + threadIdx.x;
  if (n >= N) return;
  int rd = row_d[n], rs = row_s[n];
#pragma unroll
  for (int c = 0; c < NCHK; ++c) {
    int t = Hd[(size_t)c * N + n]; Hd[(size_t)c * N + n] = rd; rd += t;
    t = Hs[(size_t)c * N + n];     Hs[(size_t)c * N + n] = rs; rs += t;
  }
}

__global__ __launch_bounds__(256) void scatter_kernel(
    const int* __restrict__ src, const int* __restrict__ dst,
    const int* __restrict__ Hd, const int* __restrict__ Hs,
    int* __restrict__ col_d, int* __restrict__ col_s, int E, int N, int chunk) {
  int c = blockIdx.x, g = blockIdx.y;
  int lo = (int)((long long)N * g / NGRP);
  int hi = (int)((long long)N * (g + 1) / NGRP);
  int range = hi - lo;
  __shared__ int curd[RMAX];
  __shared__ int curs[RMAX];
  for (int i = threadIdx.x; i < range; i += 256) {
    curd[i] = Hd[(size_t)c * N + lo + i];
    curs[i] = Hs[(size_t)c * N + lo + i];
  }
  __syncthreads();
  int e0 = c * chunk, e1 = min(E, e0 + chunk);
  for (int e = e0 + (int)threadIdx.x * 4; e < e1; e += 1024) {
    if (e + 4 <= e1) {
      int4 s4 = *(const int4*)(src + e);
      int4 d4 = *(const int4*)(dst + e);
      if (d4.x >= lo && d4.x < hi) { int p = atomicAdd(&curd[d4.x - lo], 1); col_d[p] = s4.x; }
      if (d4.y >= lo && d4.y < hi) { int p = atomicAdd(&curd[d4.y - lo], 1); col_d[p] = s4.y; }
      if (d4.z >= lo && d4.z < hi) { int p = atomicAdd(&curd[d4.z - lo], 1); col_d[p] = s4.z; }
      if (d4.w >= lo && d4.w < hi) { int p = atomicAdd(&curd[d4.w - lo], 1); col_d[p] = s4.w; }
      if (s4.x >= lo && s4.x < hi) { int p = atomicAdd(&curs[s4.x - lo], 1); col_s[p] = d4.x; }
      if (s4.y >= lo && s4.y < hi) { int p = atomicAdd(&curs[s4.y - lo], 1); col_s[p] = d4.y; }
      if (s4.z >= lo && s4.z < hi) { int p = atomicAdd(&curs[s4.z - lo], 1); col_s[p] = d4.z; }
      if (s4.w >= lo && s4.w < hi) { int p = atomicAdd(&curs[s4.w - lo], 1); col_s[p] = d4.w; }
    } else {
      for (int k = e; k < e1; ++k) {
        int s = src[k], d = dst[k];
        if (d >= lo && d < hi) { int p = atomicAdd(&curd[d - lo], 1); col_d[p] = s; }
        if (s >= lo && s < hi) { int p = atomicAdd(&curs[s - lo], 1); col_s[p] = d; }
      }
    }
  }
}

// ---------------- aggregation: wave per node, lane = feature; y selects direction ----------------

__global__ __launch_bounds__(256) void agg2_kernel(
    const float* __restrict__ h,
    const int* __restrict__ row_d, const int* __restrict__ col_d, float* __restrict__ g1,
    const int* __restrict__ row_s, const int* __restrict__ col_s, float* __restrict__ g2,
    int N) {
  const int* row = (blockIdx.y == 0) ? row_d : row_s;
  const int* col = (blockIdx.y == 0) ? col_d : col_s;
  float* outp = (blockIdx.y == 0) ? g1 : g2;
  int wid = blockIdx.x * 4 + (threadIdx.x >> 6);
  int lane = threadIdx.x & 63;
  if (wid >= N) return;
  int s0 = row[wid], s1 = row[wid + 1];
  float a0 = 0.f, a1 = 0.f, a2 = 0.f, a3 = 0.f;
  int p = s0;
  for (; p + 8 <= s1; p += 8) {
    int n0 = col[p], n1 = col[p + 1], n2 = col[p + 2], n3 = col[p + 3];
    int n4 = col[p + 4], n5 = col[p + 5], n6 = col[p + 6], n7 = col[p + 7];
    a0 += h[(size_t)n0 * NDIM + lane];
    a1 += h[(size_t)n1 * NDIM + lane];
    a2 += h[(size_t)n2 * NDIM + lane];
    a3 += h[(size_t)n3 * NDIM + lane];
    a0 += h[(size_t)n4 * NDIM + lane];
    a1 += h[(size_t)n5 * NDIM + lane];
    a2 += h[(size_t)n6 * NDIM + lane];
    a3 += h[(size_t)n7 * NDIM + lane];
  }
  for (; p + 4 <= s1; p += 4) {
    int n0 = col[p], n1 = col[p + 1], n2 = col[p + 2], n3 = col[p + 3];
    a0 += h[(size_t)n0 * NDIM + lane];
    a1 += h[(size_t)n1 * NDIM + lane];
    a2 += h[(size_t)n2 * NDIM + lane];
    a3 += h[(size_t)n3 * NDIM + lane];
  }
  for (; p < s1; ++p) a0 += h[(size_t)col[p] * NDIM + lane];
  float sum = (a0 + a1) + (a2 + a3);
  int cnt = s1 - s0;
  float inv = cnt > 0 ? 1.f / (float)cnt : 0.f;
  outp[(size_t)wid * NDIM + lane] = sum * inv;
}

// ---------------- combine: 64-node LDS tile, lane=node, wave=16 outputs ----------------
// h_out = relu(h@R^T + b + g1@W1^T + g2@W2^T); weights k-major, register
// double-buffered (1-deep) so loads for k+1 overlap FMAs of k.

__global__ __launch_bounds__(256, 3) void combine_kernel(
    const float* __restrict__ h, const float* __restrict__ g1,
    const float* __restrict__ g2, const float* __restrict__ wrT,
    const float* __restrict__ w1T, const float* __restrict__ w2T,
    const float* __restrict__ bias, float* __restrict__ hout, int N) {
  __shared__ float Ht[64][65];
  __shared__ float G1t[64][65];
  __shared__ float G2t[64][65];
  int tid = threadIdx.x;
  int n0 = blockIdx.x * 64;
  int r = tid >> 2;
  bool ok = (n0 + r) < N;
  const float4* hp = (const float4*)(h  + (size_t)(n0 + r) * NDIM);
  const float4* q1 = (const float4*)(g1 + (size_t)(n0 + r) * NDIM);
  const float4* q2 = (const float4*)(g2 + (size_t)(n0 + r) * NDIM);
#pragma unroll
  for (int i = 0; i < 4; ++i) {
    int q = (tid & 3) + i * 4;
    float4 a = ok ? hp[q] : float4{0.f, 0.f, 0.f, 0.f};
    float4 b = ok ? q1[q] : float4{0.f, 0.f, 0.f, 0.f};
    float4 c = ok ? q2[q] : float4{0.f, 0.f, 0.f, 0.f};
    Ht[r][q*4+0]=a.x;  Ht[r][q*4+1]=a.y;  Ht[r][q*4+2]=a.z;  Ht[r][q*4+3]=a.w;
    G1t[r][q*4+0]=b.x; G1t[r][q*4+1]=b.y; G1t[r][q*4+2]=b.z; G1t[r][q*4+3]=b.w;
    G2t[r][q*4+0]=c.x; G2t[r][q*4+1]=c.y; G2t[r][q*4+2]=c.z; G2t[r][q*4+3]=c.w;
  }
  __syncthreads();
  int w = __builtin_amdgcn_readfirstlane(tid >> 6);
  int lane = tid & 63;
  int ob = w * 16;
  float acc[16];
#pragma unroll
  for (int o = 0; o < 16; ++o) acc[o] = bias[ob + o];
  float4 nA[4], nB[4], nC[4];
  float nh, n1v, n2v;
  {
    const float4* pa = (const float4*)(wrT + ob);
    const float4* pb = (const float4*)(w1T + ob);
    const float4* pc = (const float4*)(w2T + ob);
#pragma unroll
    for (int j = 0; j < 4; ++j) { nA[j] = pa[j]; nB[j] = pb[j]; nC[j] = pc[j]; }
    nh = Ht[lane][0]; n1v = G1t[lane][0]; n2v = G2t[lane][0];
  }
  for (int k = 0; k < 64; ++k) {
    float4 A[4], B[4], C[4];
    float hv = nh, v1 = n1v, v2 = n2v;
#pragma unroll
    for (int j = 0; j < 4; ++j) { A[j] = nA[j]; B[j] = nB[j]; C[j] = nC[j]; }
    if (k < 63) {
      int k1 = k + 1;
      const float4* pa = (const float4*)(wrT + k1 * 64 + ob);
      const float4* pb = (const float4*)(w1T + k1 * 64 + ob);
      const float4* pc = (const float4*)(w2T + k1 * 64 + ob);
#pragma unroll
      for (int j = 0; j < 4; ++j) { nA[j] = pa[j]; nB[j] = pb[j]; nC[j] = pc[j]; }
      nh = Ht[lane][k1]; n1v = G1t[lane][k1]; n2v = G2t[lane][k1];
    }
#pragma unroll
    for (int j = 0; j < 4; ++j) {
      acc[4*j+0] += hv * A[j].x + v1 * B[j].x + v2 * C[j].x;
      acc[4*j+1] += hv * A[j].y + v1 * B[j].y + v2 * C[j].y;
      acc[4*j+2] += hv * A[j].z + v1 * B[j].z + v2 * C[j].z;
      acc[4*j+3] += hv * A[j].w + v1 * B[j].w + v2 * C[j].w;
    }
  }
  int node = n0 + lane;
  if (node < N) {
    float4* op = (float4*)(hout + (size_t)node * NDIM + ob);
#pragma unroll
    for (int j = 0; j < 4; ++j) {
      float4 v;
      v.x = fmaxf(acc[4*j+0], 0.f);
      v.y = fmaxf(acc[4*j+1], 0.f);
      v.z = fmaxf(acc[4*j+2], 0.f);
      v.w = fmaxf(acc[4*j+3], 0.f);
      op[j] = v;
    }
  }
}

// ---------------- final: 64-node LDS tile (4 input bufs), lane=node ----------------

__global__ __launch_bounds__(256, 2) void final_kernel(
    const float* __restrict__ x, const float* __restrict__ h1,
    const float* __restrict__ h2, const float* __restrict__ h3,
    const float* __restrict__ fwT, const float* __restrict__ fb,
    float* __restrict__ outp, int N) {
  __shared__ float Ft[4][64][65];
  int tid = threadIdx.x;
  int n0 = blockIdx.x * 64;
  int r = tid >> 2;
  bool ok = (n0 + r) < N;
  const float* bufs[4] = {x, h1, h2, h3};
#pragma unroll
  for (int b = 0; b < 4; ++b) {
    const float4* ip = (const float4*)(bufs[b] + (size_t)(n0 + r) * NDIM);
#pragma unroll
    for (int i = 0; i < 4; ++i) {
      int q = (tid & 3) + i * 4;
      float4 v = ok ? ip[q] : float4{0.f, 0.f, 0.f, 0.f};
      Ft[b][r][q*4+0]=v.x; Ft[b][r][q*4+1]=v.y; Ft[b][r][q*4+2]=v.z; Ft[b][r][q*4+3]=v.w;
    }
  }
  __syncthreads();
  int w = __builtin_amdgcn_readfirstlane(tid >> 6);
  int lane = tid & 63;
  int ob = w * 16;
  float acc[16];
#pragma unroll
  for (int o = 0; o < 16; ++o) acc[o] = fb[ob + o];
  float4 nW[4];
  float nv;
  {
    const float4* wp = (const float4*)(fwT + ob);
#pragma unroll
    for (int j = 0; j < 4; ++j) nW[j] = wp[j];
    nv = Ft[0][lane][0];
  }
  for (int k = 0; k < 256; ++k) {
    float4 W[4];
    float v = nv;
#pragma unroll
    for (int j = 0; j < 4; ++j) W[j] = nW[j];
    if (k < 255) {
      int k1 = k + 1;
      const float4* wp = (const float4*)(fwT + k1 * 64 + ob);
#pragma unroll
      for (int j = 0; j < 4; ++j) nW[j] = wp[j];
      nv = Ft[k1 >> 6][lane][k1 & 63];
    }
#pragma unroll
    for (int j = 0; j < 4; ++j) {
      acc[4*j+0] += v * W[j].x;
      acc[4*j+1] += v * W[j].y;
      acc[4*j+2] += v * W[j].z;
      acc[4*j+3] += v * W[j].w;
    }
  }
  int node = n0 + lane;
  if (node < N) {
    float4* op = (float4*)(outp + (size_t)node * NDIM + ob);
#pragma unroll
    for (int j = 0; j < 4; ++j) {
      float4 v;
      v.x = acc[4*j+0]; v.y = acc[4*j+1]; v.z = acc[4*j+2]; v.w = acc[4*j+3];
      op[j] = v;
    }
  }
}

// ---------------- launch ----------------

extern "C" void kernel_launch(void* const* d_in, const int* in_sizes, int n_in,
                              void* d_out, int out_size, void* d_ws, size_t ws_size,
                              hipStream_t stream) {
  const float* x     = (const float*)d_in[0];
  const int*   ei    = (const int*)d_in[1];
  const float* lin1  = (const float*)d_in[2];
  const float* lin2  = (const float*)d_in[3];
  const float* rootw = (const float*)d_in[4];
  const float* rootb = (const float*)d_in[5];
  const float* fw    = (const float*)d_in[6];
  const float* fb    = (const float*)d_in[7];
  float* out = (float*)d_out;

  int N = in_sizes[0] / NDIM;
  int E = in_sizes[1] / 2;
  const int* src = ei;
  const int* dst = ei + E;

  int* ip = (int*)d_ws;
  int* Hd    = ip; ip += (size_t)NCHK * N;
  int* Hs    = ip; ip += (size_t)NCHK * N;
  int* deg_d = ip; ip += N;
  int* deg_s = ip; ip += N;
  int* row_d = ip; ip += N + 1;
  int* row_s = ip; ip += N + 1;
  int* bsum  = ip; ip += 256;
  int* col_d = ip; ip += E;
  int* col_s = ip; ip += E;
  uintptr_t fbase = (((uintptr_t)ip) + 255) & ~(uintptr_t)255;
  float* fwT = (float*)fbase;
  float* wrT = fwT + 16384;
  float* w1T = wrT + 12288;
  float* w2T = w1T + 12288;
  float* h1  = w2T + 12288;
  float* h2 = h1 + (size_t)N * NDIM;
  float* h3 = h2 + (size_t)N * NDIM;
  float* g1 = h3 + (size_t)N * NDIM;
  float* g2 = g1 + (size_t)N * NDIM;

  int chunk = (E + NCHK - 1) / NCHK;
  int nb = (N + SCAN_ELEMS - 1) / SCAN_ELEMS;
  int nblk = (N + 255) / 256;

  transpose_kernel<<<112, 256, 0, stream>>>(fw, rootw, lin1, lin2, fwT, wrT, w1T, w2T);
  hist_kernel<<<dim3(NCHK, NGRP), 256, 0, stream>>>(src, dst, Hd, Hs, E, N, chunk);
  degsum_kernel<<<nblk, 256, 0, stream>>>(Hd, Hs, deg_d, deg_s, N);
  scan_partial<<<dim3(nb, 2), 256, 0, stream>>>(deg_d, deg_s, bsum, N, nb);
  scan_bsum<<<1, 256, 0, stream>>>(bsum, nb);
  scan_final<<<dim3(nb, 2), 256, 0, stream>>>(deg_d, deg_s, bsum, row_d, row_s, N, nb);
  cursor_kernel<<<nblk, 256, 0, stream>>>(Hd, Hs, row_d, row_s, N);
  scatter_kernel<<<dim3(NCHK, NGRP), 256, 0, stream>>>(src, dst, Hd, Hs,
                                                       col_d, col_s, E, N, chunk);

  int ab = (N + 3) / 4;
  int tgrid = (N + 63) / 64;     // 64-node tiles for combine/final
  const float* hbufs[4] = {x, h1, h2, h3};
  for (int l = 0; l < 3; ++l) {
    const float* hin = hbufs[l];
    float* hout = (float*)hbufs[l + 1];
    agg2_kernel<<<dim3(ab, 2), 256, 0, stream>>>(hin, row_d, col_d, g1,
                                                 row_s, col_s, g2, N);
    combine_kernel<<<tgrid, 256, 0, stream>>>(hin, g1, g2,
                                              wrT + (size_t)l * 4096,
                                              w1T + (size_t)l * 4096,
                                              w2T + (size_t)l * 4096,
                                              rootb + (size_t)l * 64, hout, N);
  }
  final_kernel<<<tgrid, 256, 0, stream>>>(x, h1, h2, h3, fwT, fb, out, N);
}